// Round 17
// baseline (105.998 us; speedup 1.0000x reference)
//
#include <hip/hip_runtime.h>

#define PI_F 3.14159265358979f
#define CAP 256

#if __has_builtin(__builtin_amdgcn_exp2f)
#define EXP2F(x) __builtin_amdgcn_exp2f(x)
#else
#define EXP2F(x) exp2f(x)
#endif

// hardware sin/cos: input in REVOLUTIONS (D = sin(S0*2pi)); valid for |x| small.
__device__ __forceinline__ float hw_sin_rev(float q){ float r; asm("v_sin_f32 %0, %1" : "=v"(r) : "v"(q)); return r; }
__device__ __forceinline__ float hw_cos_rev(float q){ float r; asm("v_cos_f32 %0, %1" : "=v"(r) : "v"(q)); return r; }

// ---- packed complex type: <2 x float> so the backend can select v_pk_*_f32 ----
typedef float cf2 __attribute__((ext_vector_type(2)));
__device__ __forceinline__ cf2 mkc(float x, float y){ cf2 r; r.x = x; r.y = y; return r; }
__device__ __forceinline__ cf2 cmulv(cf2 a, cf2 b){
    cf2 bs = mkc(-b.y, b.x);
#if __has_builtin(__builtin_elementwise_fma)
    return __builtin_elementwise_fma(a.yy, bs, a.xx * b);
#else
    return a.xx * b + a.yy * bs;
#endif
}
__device__ __forceinline__ cf2 cjg(cf2 a){ return mkc(a.x, -a.y); }
__device__ __forceinline__ cf2 ci(cf2 a){ return mkc(-a.y, a.x); }   // i*a

// COMPILER-ONLY fence: LDS pipe is in-order per wave (buffers are wave-private),
// so cross-lane visibility needs no hardware drain — only a reorder barrier.
__device__ __forceinline__ void cfence() {
    asm volatile("" ::: "memory");
}

// ---- 16-pt unnormalized inverse DFT (sign +), in-place, fully unrolled ----
#define W16_C8 0.923879532511287f
#define W16_S8 0.382683432365090f
#define W16_R2 0.707106781186548f
__device__ __forceinline__ void idft16_full(cf2* x)
{
    cf2 u[16];
#pragma unroll
    for (int b0 = 0; b0 < 4; ++b0) {
        cf2 x0 = x[b0], x1 = x[4+b0], x2 = x[8+b0], x3 = x[12+b0];
        cf2 t0 = x0 + x2, t1 = x0 - x2;
        cf2 t2 = x1 + x3, t3 = x1 - x3;
        cf2 it3 = ci(t3);
        u[b0*4+0] = t0 + t2;
        u[b0*4+1] = t1 + it3;
        u[b0*4+2] = t0 - t2;
        u[b0*4+3] = t1 - it3;
    }
    u[4+1]  = cmulv(u[4+1],  mkc( W16_C8,  W16_S8));
    u[4+2]  = cmulv(u[4+2],  mkc( W16_R2,  W16_R2));
    u[4+3]  = cmulv(u[4+3],  mkc( W16_S8,  W16_C8));
    u[8+1]  = cmulv(u[8+1],  mkc( W16_R2,  W16_R2));
    u[8+2]  = ci(u[8+2]);
    u[8+3]  = cmulv(u[8+3],  mkc(-W16_R2,  W16_R2));
    u[12+1] = cmulv(u[12+1], mkc( W16_S8,  W16_C8));
    u[12+2] = cmulv(u[12+2], mkc(-W16_R2,  W16_R2));
    u[12+3] = cmulv(u[12+3], mkc(-W16_C8, -W16_S8));
#pragma unroll
    for (int a0 = 0; a0 < 4; ++a0) {
        cf2 x0 = u[a0], x1 = u[4+a0], x2 = u[8+a0], x3 = u[12+a0];
        cf2 t0 = x0 + x2, t1 = x0 - x2;
        cf2 t2 = x1 + x3, t3 = x1 - x3;
        cf2 it3 = ci(t3);
        x[a0+0]  = t0 + t2;
        x[a0+4]  = t1 + it3;
        x[a0+8]  = t0 - t2;
        x[a0+12] = t1 - it3;
    }
}
__device__ __forceinline__ void idft16_low8(cf2* x)
{
    cf2 u[16];
#pragma unroll
    for (int b0 = 0; b0 < 4; ++b0) {
        cf2 x0 = x[b0], x1 = x[4+b0], x2 = x[8+b0], x3 = x[12+b0];
        cf2 t0 = x0 + x2, t1 = x0 - x2;
        cf2 t2 = x1 + x3, t3 = x1 - x3;
        cf2 it3 = ci(t3);
        u[b0*4+0] = t0 + t2;
        u[b0*4+1] = t1 + it3;
        u[b0*4+2] = t0 - t2;
        u[b0*4+3] = t1 - it3;
    }
    u[4+1]  = cmulv(u[4+1],  mkc( W16_C8,  W16_S8));
    u[4+2]  = cmulv(u[4+2],  mkc( W16_R2,  W16_R2));
    u[4+3]  = cmulv(u[4+3],  mkc( W16_S8,  W16_C8));
    u[8+1]  = cmulv(u[8+1],  mkc( W16_R2,  W16_R2));
    u[8+2]  = ci(u[8+2]);
    u[8+3]  = cmulv(u[8+3],  mkc(-W16_R2,  W16_R2));
    u[12+1] = cmulv(u[12+1], mkc( W16_S8,  W16_C8));
    u[12+2] = cmulv(u[12+2], mkc(-W16_R2,  W16_R2));
    u[12+3] = cmulv(u[12+3], mkc(-W16_C8, -W16_S8));
#pragma unroll
    for (int a0 = 0; a0 < 4; ++a0) {
        cf2 x0 = u[a0], x1 = u[4+a0], x2 = u[8+a0], x3 = u[12+a0];
        cf2 t0 = x0 + x2, t1 = x0 - x2;
        cf2 t2 = x1 + x3, t3 = x1 - x3;
        cf2 it3 = ci(t3);
        x[a0+0] = t0 + t2;
        x[a0+4] = t1 + it3;
    }
}

// ---------------- kernel A+B fused: softmax stats (blocks 0..1023) | nz lists (1024..1537) ----
__global__ __launch_bounds__(256) void kfused(const float* __restrict__ sel,
                                              const float* __restrict__ items,
                                              float* __restrict__ rowmax,
                                              float* __restrict__ rowinv,
                                              int* __restrict__ kidx,
                                              float* __restrict__ kval,
                                              int* __restrict__ ncol)
{
    const int tid = threadIdx.x;
    if (blockIdx.x < 1024) {
        // ---- ksoft body ----
        const int row = blockIdx.x;
        const float4* p4 = (const float4*)(sel + (size_t)row * 4096);
        float4 v[4];
        float mx = -3.0e38f;
#pragma unroll
        for (int i = 0; i < 4; ++i) {
            v[i] = p4[tid + (i<<8)];
            mx = fmaxf(mx, fmaxf(fmaxf(v[i].x, v[i].y), fmaxf(v[i].z, v[i].w)));
        }
#pragma unroll
        for (int o = 32; o >= 1; o >>= 1) mx = fmaxf(mx, __shfl_xor(mx, o));
        __shared__ float red[8];
        const int wv = tid >> 6;
        if ((tid & 63) == 0) red[wv] = mx;
        __syncthreads();
        mx = fmaxf(fmaxf(red[0], red[1]), fmaxf(red[2], red[3]));
        float s = 0.0f;
#pragma unroll
        for (int i = 0; i < 4; ++i) {
            s += __expf(v[i].x - mx) + __expf(v[i].y - mx) + __expf(v[i].z - mx) + __expf(v[i].w - mx);
        }
#pragma unroll
        for (int o = 32; o >= 1; o >>= 1) s += __shfl_xor(s, o);
        if ((tid & 63) == 0) red[4 + wv] = s;
        __syncthreads();
        if (tid == 0) {
            rowmax[row] = mx;
            rowinv[row] = 1.0f / (red[4] + red[5] + red[6] + red[7]);
        }
    } else {
        // ---- kfill body ----
        const int c = blockIdx.x - 1024;
        if (c >= 514) return;
        const int wv = tid >> 6;
        const int lane = tid & 63;
        __shared__ int wcnt[4];

        const int kc0 = wv << 10;
        float vv[16];
        int cnt = 0;
#pragma unroll
        for (int it = 0; it < 16; ++it) {
            const int k = kc0 + (it << 6) + lane;
            const float v = items[(size_t)k * 514 + c];
            vv[it] = v;
            unsigned long long mb = __ballot(v != 0.0f);
            cnt += __popcll(mb);
        }
        if (lane == 0) wcnt[wv] = cnt;
        __syncthreads();

        int base = 0;
#pragma unroll
        for (int q = 0; q < 4; ++q) if (q < wv) base += wcnt[q];

        const unsigned long long ltmask = (lane == 63) ? 0x7fffffffffffffffull
                                                       : ((1ull << lane) - 1ull);
#pragma unroll
        for (int it = 0; it < 16; ++it) {
            const float v = vv[it];
            const bool nz = (v != 0.0f);
            unsigned long long mb = __ballot(nz);
            if (nz) {
                const int slot = base + __popcll(mb & ltmask);
                if (slot < CAP) {
                    kidx[c * CAP + slot] = kc0 + (it << 6) + lane;
                    kval[c * CAP + slot] = v;
                }
            }
            base += __popcll(mb);
        }
        if (tid == 0) ncol[c] = wcnt[0] + wcnt[1] + wcnt[2] + wcnt[3];
    }
}

// ---------------- kernel A2: W^T[k][m] = softmax weight, tiled transpose ----------------
__global__ __launch_bounds__(256) void kT(const float* __restrict__ sel,
                                          const float* __restrict__ rowmax,
                                          const float* __restrict__ rowinv,
                                          float* __restrict__ WT)
{
    __shared__ float tile[64][65];
    __shared__ float smx[64], sinv[64];
    const int t = threadIdx.x;
    const int k0 = blockIdx.x * 64;
    const int m0 = blockIdx.y * 64;

    if (t < 64) { smx[t] = rowmax[m0 + t]; sinv[t] = rowinv[m0 + t]; }
    __syncthreads();

    const int m_l = t >> 4;
    const int k_l4 = (t & 15) << 2;
#pragma unroll
    for (int i = 0; i < 4; ++i) {
        const int ml = m_l + (i << 4);
        const float mxv = smx[ml], invv = sinv[ml];
        float4 v = *(const float4*)(sel + (size_t)(m0 + ml) * 4096 + k0 + k_l4);
        tile[k_l4 + 0][ml] = __expf(v.x - mxv) * invv;
        tile[k_l4 + 1][ml] = __expf(v.y - mxv) * invv;
        tile[k_l4 + 2][ml] = __expf(v.z - mxv) * invv;
        tile[k_l4 + 3][ml] = __expf(v.w - mxv) * invv;
    }
    __syncthreads();

    const int k_l = t >> 2;
    const int mb = (t & 3) << 2;
#pragma unroll
    for (int i = 0; i < 4; ++i) {
        const int ml = mb + (i << 4);
        float4 w = make_float4(tile[k_l][ml], tile[k_l][ml+1], tile[k_l][ml+2], tile[k_l][ml+3]);
        *(float4*)(WT + (size_t)(k0 + k_l) * 1024 + m0 + ml) = w;
    }
}

// ---------------- kernel B2: sparse matmul + transform -> P4 (float4 {L,M,C,S} per bin) ----
__global__ __launch_bounds__(256) void kspmm(const float* __restrict__ WT,
                                             const int* __restrict__ kidx,
                                             const float* __restrict__ kval,
                                             const int* __restrict__ ncol,
                                             float2* __restrict__ P2)
{
    __shared__ int   ski[CAP];
    __shared__ float skv[CAP];
    const int c = blockIdx.y;
    const int m = (blockIdx.x << 8) + threadIdx.x;
    const int nn = min(ncol[c], CAP);
    if (threadIdx.x < nn) {
        ski[threadIdx.x] = kidx[c * CAP + threadIdx.x];
        skv[threadIdx.x] = kval[c * CAP + threadIdx.x];
    }
    __syncthreads();

    float acc = 0.0f;
    int i = 0;
    for (; i + 4 <= nn; i += 4) {
        const int k0 = ski[i], k1 = ski[i+1], k2 = ski[i+2], k3 = ski[i+3];
        const float v0 = skv[i], v1 = skv[i+1], v2 = skv[i+2], v3 = skv[i+3];
        const float w0 = WT[(size_t)k0 * 1024 + m];
        const float w1 = WT[(size_t)k1 * 1024 + m];
        const float w2 = WT[(size_t)k2 * 1024 + m];
        const float w3 = WT[(size_t)k3 * 1024 + m];
        acc = fmaf(v0, w0, acc);
        acc = fmaf(v1, w1, acc);
        acc = fmaf(v2, w2, acc);
        acc = fmaf(v3, w3, acc);
    }
    for (; i < nn; ++i) {
        acc = fmaf(skv[i], WT[(size_t)ski[i] * 1024 + m], acc);
    }

    const float x = acc;
    if (c < 257) {
        float mm = 0.9999f / (1.0f + __expf(-x));
        P2[((size_t)m * 257 + c) * 2] = make_float2(__log2f(mm), mm);
    } else {
        float e2 = __expf(2.0f * x);
        float th = (e2 - 1.0f) / (e2 + 1.0f);
        float ph = PI_F * th;
        float sn, cs;
        __sincosf(ph, &sn, &cs);
        P2[((size_t)m * 257 + (c - 257)) * 2 + 1] = make_float2(cs, sn);
    }
}

// ---------------- kernel C: 16 lanes per j-block, radix-16^2 IFFT, packed-f32 complex ----
// 1/512 scale folded into the exp2 argument; transpose twiddles via v_sin/v_cos (revolutions).
__global__ __launch_bounds__(256) void kres(const float4* __restrict__ P4, float* __restrict__ out)
{
    const int tid = threadIdx.x;
    const int lane = tid & 63;
    const int wv = tid >> 6;
    const int g = lane >> 4;
    const int gl = lane & 15;
    const int item = blockIdx.x >> 3;
    const int jg = blockIdx.x & 7;

    __shared__ cf2 U[16 * 256];
    cf2* ub = U + (wv * 4 + g) * 256;

    const int j = jg * 16 + wv * 4 + g;
    const float fj = (float)j;
    const float gf = (j > 0) ? 1.0f : 0.0f;
    const float sg = (gl & 1) ? -gf : gf;     // (-1)^c * gf, c = gl+16r

    const int pb4 = item * 257;

    // ---- phase 1: load bins, build S (regs, pre-scaled by 1/512) and V -> LDS
    cf2 S[16];
#pragma unroll
    for (int r = 0; r < 16; ++r) {
        float4 q = P4[pb4 + gl + 16*r];       // {L, M, C, S}
        float p = EXP2F(fmaf(fj, q.x, -9.0f));   // m^j / 512
        cf2 F = p * mkc(q.z, q.w);
        cf2 Sv = (q.y + sg) * F;
        cf2 Vv = (q.y - sg) * F;
        if (gl == 0 && r == 0) { Sv.y = 0.0f; Vv.y = 0.0f; }  // DC imag dropped
        S[r] = Sv;
        ub[gl + 16*r] = Vv;
    }
    // bin 256 (group-uniform; computed by every lane, kept in registers)
    float4 q6 = P4[pb4 + 256];
    float pc6 = EXP2F(fmaf(fj, q6.x, -9.0f)) * q6.z;
    const float S6 = (q6.y + gf) * pc6;
    const float V6 = (q6.y - gf) * pc6;
    cfence();

    // ---- phase 2: Hann 3-tap, H into S regs
    float H6;
#pragma unroll
    for (int r = 0; r < 16; ++r) {
        const int c = gl + 16*r;
        const int im = (c == 0) ? 1 : c - 1;
        cf2 Vm = ub[im];
        if (c == 0) Vm.y = -Vm.y;             // hermitian V[-1] = conj V[1]
        cf2 Vp;
        if (r == 15) Vp = (gl == 15) ? mkc(V6, 0.0f) : ub[c + 1];
        else         Vp = ub[c + 1];
        S[r] = 0.5f * S[r] - 0.25f * (Vm + Vp);
    }
    H6 = 0.5f*S6 - 0.5f*ub[255].x;            // read before overwrite
    cfence();

    // write H over V (same-wave in-order)
#pragma unroll
    for (int r = 0; r < 16; ++r) ub[gl + 16*r] = S[r];
    cfence();

    // ---- phase 3: half-size packing -> Z (into S regs); scale already folded
    cf2 zw0 = mkc(hw_cos_rev((float)gl * (1.0f/512.0f)),
                  hw_sin_rev((float)gl * (1.0f/512.0f)));
    const float ZKC[16] = { 1.0f, 0.980785280403230f, 0.923879532511287f, 0.831469612302545f,
                            0.707106781186548f, 0.555570233019602f, 0.382683432365090f, 0.195090322016128f,
                            0.0f, -0.195090322016128f, -0.382683432365090f, -0.555570233019602f,
                            -0.707106781186548f, -0.831469612302545f, -0.923879532511287f, -0.980785280403230f };
    const float ZKS[16] = { 0.0f, 0.195090322016128f, 0.382683432365090f, 0.555570233019602f,
                            0.707106781186548f, 0.831469612302545f, 0.923879532511287f, 0.980785280403230f,
                            1.0f, 0.980785280403230f, 0.923879532511287f, 0.831469612302545f,
                            0.707106781186548f, 0.555570233019602f, 0.382683432365090f, 0.195090322016128f };
#pragma unroll
    for (int r = 0; r < 16; ++r) {
        const int c = gl + 16*r;
        cf2 Hk = S[r];
        cf2 cHm;
        if (r == 0) cHm = (gl == 0) ? mkc(H6, 0.0f) : cjg(ub[256 - c]);
        else        cHm = cjg(ub[256 - c]);
        cf2 w = cmulv(mkc(ZKC[r], ZKS[r]), zw0);
        cf2 A = Hk + cHm;
        cf2 B = Hk - cHm;
        S[r] = A + cmulv(ci(w), B);
    }
    cfence();   // all reads done before transpose writes (same buffer)

    // ---- FFT step 1: lane-local 16-pt IDFT over k2 (register axis); k1 = gl
    idft16_full(S);

    // ---- twiddle e^{2pi i k1 n1/256} via v_sin/v_cos + transpose write (XOR-swizzled)
    {
        const float glf = (float)gl * (1.0f/256.0f);
        ub[(gl << 4) | (0 ^ gl)] = S[0];
#pragma unroll
        for (int n1 = 1; n1 < 16; ++n1) {
            const float q = (float)n1 * glf;     // gl*n1/256 < 1 revolution
            cf2 ww = mkc(hw_cos_rev(q), hw_sin_rev(q));
            ub[(gl << 4) | (n1 ^ gl)] = cmulv(S[n1], ww);
        }
    }
    cfence();

    // ---- transpose read: lane gl becomes n1 = gl; T[k1]
    cf2 T[16];
#pragma unroll
    for (int k1 = 0; k1 < 16; ++k1) T[k1] = ub[(k1 << 4) | (gl ^ k1)];

    // ---- FFT step 2: lane-local 16-pt IDFT over k1, outputs n2 = 0..7 only
    idft16_low8(T);

    // ---- store: z[n1 + 16 n2] -> out cf2 slot (j<<7) + gl + 16*n2
    cf2* o2 = (cf2*)out + (size_t)item * 16384 + (j << 7);
#pragma unroll
    for (int n2 = 0; n2 < 8; ++n2) o2[gl + 16*n2] = T[n2];
}

extern "C" void kernel_launch(void* const* d_in, const int* in_sizes, int n_in,
                              void* d_out, int out_size, void* d_ws, size_t ws_size,
                              hipStream_t stream)
{
    const float* sel   = (const float*)d_in[0];   // (8,32,4,4096) f32 -> [1024][4096]
    const float* items = (const float*)d_in[1];   // (4096,514) f32
    float* out = (float*)d_out;                   // [1024][32768] f32
    float* ws  = (float*)d_ws;

    // Scratch in d_out (all dead before kres rewrites out):
    float* WT     = out;                          // 4096*1024 floats
    float* rowmax = out + 4194304;                // 1024
    float* rowinv = out + 4195328;                // 1024
    int*   ncol   = (int*)(out + 4196352);        // 514
    int*   kidx   = (int*)(out + 4196866);        // 514*CAP
    float* kval   = (float*)(out + 4196866 + 514*CAP);
    float4* P4    = (float4*)ws;                  // 1024*257 float4

    kfused<<<1538, 256, 0, stream>>>(sel, items, rowmax, rowinv, kidx, kval, ncol);
    kT<<<dim3(64, 16), 256, 0, stream>>>(sel, rowmax, rowinv, WT);
    kspmm<<<dim3(4, 514), 256, 0, stream>>>(WT, kidx, kval, ncol, (float2*)ws);
    kres<<<8192, 256, 0, stream>>>(P4, out);
}

// Round 18
// 105.195 us; speedup vs baseline: 1.0076x; 1.0076x over previous
//
#include <hip/hip_runtime.h>

#define PI_F 3.14159265358979f
#define CAP 256

#if __has_builtin(__builtin_amdgcn_exp2f)
#define EXP2F(x) __builtin_amdgcn_exp2f(x)
#else
#define EXP2F(x) exp2f(x)
#endif

// hardware sin/cos: input in REVOLUTIONS (D = sin(S0*2pi)); used once for zw0 only.
__device__ __forceinline__ float hw_sin_rev(float q){ float r; asm("v_sin_f32 %0, %1" : "=v"(r) : "v"(q)); return r; }
__device__ __forceinline__ float hw_cos_rev(float q){ float r; asm("v_cos_f32 %0, %1" : "=v"(r) : "v"(q)); return r; }

// ---- packed complex type: <2 x float> so the backend can select v_pk_*_f32 ----
typedef float cf2 __attribute__((ext_vector_type(2)));
__device__ __forceinline__ cf2 mkc(float x, float y){ cf2 r; r.x = x; r.y = y; return r; }
__device__ __forceinline__ cf2 cmulv(cf2 a, cf2 b){
    cf2 bs = mkc(-b.y, b.x);
#if __has_builtin(__builtin_elementwise_fma)
    return __builtin_elementwise_fma(a.yy, bs, a.xx * b);
#else
    return a.xx * b + a.yy * bs;
#endif
}
__device__ __forceinline__ cf2 cjg(cf2 a){ return mkc(a.x, -a.y); }
__device__ __forceinline__ cf2 ci(cf2 a){ return mkc(-a.y, a.x); }   // i*a

// COMPILER-ONLY fence: LDS pipe is in-order per wave (buffers are wave-private),
// so cross-lane visibility needs no hardware drain — only a reorder barrier.
__device__ __forceinline__ void cfence() {
    asm volatile("" ::: "memory");
}

// ---- 16-pt unnormalized inverse DFT (sign +), in-place, fully unrolled ----
#define W16_C8 0.923879532511287f
#define W16_S8 0.382683432365090f
#define W16_R2 0.707106781186548f
__device__ __forceinline__ void idft16_full(cf2* x)
{
    cf2 u[16];
#pragma unroll
    for (int b0 = 0; b0 < 4; ++b0) {
        cf2 x0 = x[b0], x1 = x[4+b0], x2 = x[8+b0], x3 = x[12+b0];
        cf2 t0 = x0 + x2, t1 = x0 - x2;
        cf2 t2 = x1 + x3, t3 = x1 - x3;
        cf2 it3 = ci(t3);
        u[b0*4+0] = t0 + t2;
        u[b0*4+1] = t1 + it3;
        u[b0*4+2] = t0 - t2;
        u[b0*4+3] = t1 - it3;
    }
    u[4+1]  = cmulv(u[4+1],  mkc( W16_C8,  W16_S8));
    u[4+2]  = cmulv(u[4+2],  mkc( W16_R2,  W16_R2));
    u[4+3]  = cmulv(u[4+3],  mkc( W16_S8,  W16_C8));
    u[8+1]  = cmulv(u[8+1],  mkc( W16_R2,  W16_R2));
    u[8+2]  = ci(u[8+2]);
    u[8+3]  = cmulv(u[8+3],  mkc(-W16_R2,  W16_R2));
    u[12+1] = cmulv(u[12+1], mkc( W16_S8,  W16_C8));
    u[12+2] = cmulv(u[12+2], mkc(-W16_R2,  W16_R2));
    u[12+3] = cmulv(u[12+3], mkc(-W16_C8, -W16_S8));
#pragma unroll
    for (int a0 = 0; a0 < 4; ++a0) {
        cf2 x0 = u[a0], x1 = u[4+a0], x2 = u[8+a0], x3 = u[12+a0];
        cf2 t0 = x0 + x2, t1 = x0 - x2;
        cf2 t2 = x1 + x3, t3 = x1 - x3;
        cf2 it3 = ci(t3);
        x[a0+0]  = t0 + t2;
        x[a0+4]  = t1 + it3;
        x[a0+8]  = t0 - t2;
        x[a0+12] = t1 - it3;
    }
}
__device__ __forceinline__ void idft16_low8(cf2* x)
{
    cf2 u[16];
#pragma unroll
    for (int b0 = 0; b0 < 4; ++b0) {
        cf2 x0 = x[b0], x1 = x[4+b0], x2 = x[8+b0], x3 = x[12+b0];
        cf2 t0 = x0 + x2, t1 = x0 - x2;
        cf2 t2 = x1 + x3, t3 = x1 - x3;
        cf2 it3 = ci(t3);
        u[b0*4+0] = t0 + t2;
        u[b0*4+1] = t1 + it3;
        u[b0*4+2] = t0 - t2;
        u[b0*4+3] = t1 - it3;
    }
    u[4+1]  = cmulv(u[4+1],  mkc( W16_C8,  W16_S8));
    u[4+2]  = cmulv(u[4+2],  mkc( W16_R2,  W16_R2));
    u[4+3]  = cmulv(u[4+3],  mkc( W16_S8,  W16_C8));
    u[8+1]  = cmulv(u[8+1],  mkc( W16_R2,  W16_R2));
    u[8+2]  = ci(u[8+2]);
    u[8+3]  = cmulv(u[8+3],  mkc(-W16_R2,  W16_R2));
    u[12+1] = cmulv(u[12+1], mkc( W16_S8,  W16_C8));
    u[12+2] = cmulv(u[12+2], mkc(-W16_R2,  W16_R2));
    u[12+3] = cmulv(u[12+3], mkc(-W16_C8, -W16_S8));
#pragma unroll
    for (int a0 = 0; a0 < 4; ++a0) {
        cf2 x0 = u[a0], x1 = u[4+a0], x2 = u[8+a0], x3 = u[12+a0];
        cf2 t0 = x0 + x2, t1 = x0 - x2;
        cf2 t2 = x1 + x3, t3 = x1 - x3;
        cf2 it3 = ci(t3);
        x[a0+0] = t0 + t2;
        x[a0+4] = t1 + it3;
    }
}

// ---------------- kernel A+B fused: softmax stats (blocks 0..1023) | nz lists (1024..1537) ----
__global__ __launch_bounds__(256) void kfused(const float* __restrict__ sel,
                                              const float* __restrict__ items,
                                              float* __restrict__ rowmax,
                                              float* __restrict__ rowinv,
                                              int* __restrict__ kidx,
                                              float* __restrict__ kval,
                                              int* __restrict__ ncol)
{
    const int tid = threadIdx.x;
    if (blockIdx.x < 1024) {
        // ---- ksoft body ----
        const int row = blockIdx.x;
        const float4* p4 = (const float4*)(sel + (size_t)row * 4096);
        float4 v[4];
        float mx = -3.0e38f;
#pragma unroll
        for (int i = 0; i < 4; ++i) {
            v[i] = p4[tid + (i<<8)];
            mx = fmaxf(mx, fmaxf(fmaxf(v[i].x, v[i].y), fmaxf(v[i].z, v[i].w)));
        }
#pragma unroll
        for (int o = 32; o >= 1; o >>= 1) mx = fmaxf(mx, __shfl_xor(mx, o));
        __shared__ float red[8];
        const int wv = tid >> 6;
        if ((tid & 63) == 0) red[wv] = mx;
        __syncthreads();
        mx = fmaxf(fmaxf(red[0], red[1]), fmaxf(red[2], red[3]));
        float s = 0.0f;
#pragma unroll
        for (int i = 0; i < 4; ++i) {
            s += __expf(v[i].x - mx) + __expf(v[i].y - mx) + __expf(v[i].z - mx) + __expf(v[i].w - mx);
        }
#pragma unroll
        for (int o = 32; o >= 1; o >>= 1) s += __shfl_xor(s, o);
        if ((tid & 63) == 0) red[4 + wv] = s;
        __syncthreads();
        if (tid == 0) {
            rowmax[row] = mx;
            rowinv[row] = 1.0f / (red[4] + red[5] + red[6] + red[7]);
        }
    } else {
        // ---- kfill body ----
        const int c = blockIdx.x - 1024;
        if (c >= 514) return;
        const int wv = tid >> 6;
        const int lane = tid & 63;
        __shared__ int wcnt[4];

        const int kc0 = wv << 10;
        float vv[16];
        int cnt = 0;
#pragma unroll
        for (int it = 0; it < 16; ++it) {
            const int k = kc0 + (it << 6) + lane;
            const float v = items[(size_t)k * 514 + c];
            vv[it] = v;
            unsigned long long mb = __ballot(v != 0.0f);
            cnt += __popcll(mb);
        }
        if (lane == 0) wcnt[wv] = cnt;
        __syncthreads();

        int base = 0;
#pragma unroll
        for (int q = 0; q < 4; ++q) if (q < wv) base += wcnt[q];

        const unsigned long long ltmask = (lane == 63) ? 0x7fffffffffffffffull
                                                       : ((1ull << lane) - 1ull);
#pragma unroll
        for (int it = 0; it < 16; ++it) {
            const float v = vv[it];
            const bool nz = (v != 0.0f);
            unsigned long long mb = __ballot(nz);
            if (nz) {
                const int slot = base + __popcll(mb & ltmask);
                if (slot < CAP) {
                    kidx[c * CAP + slot] = kc0 + (it << 6) + lane;
                    kval[c * CAP + slot] = v;
                }
            }
            base += __popcll(mb);
        }
        if (tid == 0) ncol[c] = wcnt[0] + wcnt[1] + wcnt[2] + wcnt[3];
    }
}

// ---------------- kernel A2: W^T[k][m] = softmax weight, tiled transpose ----------------
__global__ __launch_bounds__(256) void kT(const float* __restrict__ sel,
                                          const float* __restrict__ rowmax,
                                          const float* __restrict__ rowinv,
                                          float* __restrict__ WT)
{
    __shared__ float tile[64][65];
    __shared__ float smx[64], sinv[64];
    const int t = threadIdx.x;
    const int k0 = blockIdx.x * 64;
    const int m0 = blockIdx.y * 64;

    if (t < 64) { smx[t] = rowmax[m0 + t]; sinv[t] = rowinv[m0 + t]; }
    __syncthreads();

    const int m_l = t >> 4;
    const int k_l4 = (t & 15) << 2;
#pragma unroll
    for (int i = 0; i < 4; ++i) {
        const int ml = m_l + (i << 4);
        const float mxv = smx[ml], invv = sinv[ml];
        float4 v = *(const float4*)(sel + (size_t)(m0 + ml) * 4096 + k0 + k_l4);
        tile[k_l4 + 0][ml] = __expf(v.x - mxv) * invv;
        tile[k_l4 + 1][ml] = __expf(v.y - mxv) * invv;
        tile[k_l4 + 2][ml] = __expf(v.z - mxv) * invv;
        tile[k_l4 + 3][ml] = __expf(v.w - mxv) * invv;
    }
    __syncthreads();

    const int k_l = t >> 2;
    const int mb = (t & 3) << 2;
#pragma unroll
    for (int i = 0; i < 4; ++i) {
        const int ml = mb + (i << 4);
        float4 w = make_float4(tile[k_l][ml], tile[k_l][ml+1], tile[k_l][ml+2], tile[k_l][ml+3]);
        *(float4*)(WT + (size_t)(k0 + k_l) * 1024 + m0 + ml) = w;
    }
}

// ---------------- kernel B2: sparse matmul + transform -> P4 (float4 {L,M,C,S} per bin) ----
__global__ __launch_bounds__(256) void kspmm(const float* __restrict__ WT,
                                             const int* __restrict__ kidx,
                                             const float* __restrict__ kval,
                                             const int* __restrict__ ncol,
                                             float2* __restrict__ P2)
{
    __shared__ int   ski[CAP];
    __shared__ float skv[CAP];
    const int c = blockIdx.y;
    const int m = (blockIdx.x << 8) + threadIdx.x;
    const int nn = min(ncol[c], CAP);
    if (threadIdx.x < nn) {
        ski[threadIdx.x] = kidx[c * CAP + threadIdx.x];
        skv[threadIdx.x] = kval[c * CAP + threadIdx.x];
    }
    __syncthreads();

    float acc = 0.0f;
    int i = 0;
    for (; i + 4 <= nn; i += 4) {
        const int k0 = ski[i], k1 = ski[i+1], k2 = ski[i+2], k3 = ski[i+3];
        const float v0 = skv[i], v1 = skv[i+1], v2 = skv[i+2], v3 = skv[i+3];
        const float w0 = WT[(size_t)k0 * 1024 + m];
        const float w1 = WT[(size_t)k1 * 1024 + m];
        const float w2 = WT[(size_t)k2 * 1024 + m];
        const float w3 = WT[(size_t)k3 * 1024 + m];
        acc = fmaf(v0, w0, acc);
        acc = fmaf(v1, w1, acc);
        acc = fmaf(v2, w2, acc);
        acc = fmaf(v3, w3, acc);
    }
    for (; i < nn; ++i) {
        acc = fmaf(skv[i], WT[(size_t)ski[i] * 1024 + m], acc);
    }

    const float x = acc;
    if (c < 257) {
        float mm = 0.9999f / (1.0f + __expf(-x));
        P2[((size_t)m * 257 + c) * 2] = make_float2(__log2f(mm), mm);
    } else {
        float e2 = __expf(2.0f * x);
        float th = (e2 - 1.0f) / (e2 + 1.0f);
        float ph = PI_F * th;
        float sn, cs;
        __sincosf(ph, &sn, &cs);
        P2[((size_t)m * 257 + (c - 257)) * 2 + 1] = make_float2(cs, sn);
    }
}

// ---------------- kernel C: 16 lanes per j-block, radix-16^2 IFFT, packed-f32 complex ----
// 1/512 folded into exp2; transpose twiddles via serial cmulv recurrence (R16-proven).
__global__ __launch_bounds__(256) void kres(const float4* __restrict__ P4, float* __restrict__ out)
{
    const int tid = threadIdx.x;
    const int lane = tid & 63;
    const int wv = tid >> 6;
    const int g = lane >> 4;
    const int gl = lane & 15;
    const int item = blockIdx.x >> 3;
    const int jg = blockIdx.x & 7;

    __shared__ cf2 U[16 * 256];
    cf2* ub = U + (wv * 4 + g) * 256;

    const int j = jg * 16 + wv * 4 + g;
    const float fj = (float)j;
    const float gf = (j > 0) ? 1.0f : 0.0f;
    const float sg = (gl & 1) ? -gf : gf;     // (-1)^c * gf, c = gl+16r

    const int pb4 = item * 257;

    // ---- phase 1: load bins, build S (regs, pre-scaled by 1/512) and V -> LDS
    cf2 S[16];
#pragma unroll
    for (int r = 0; r < 16; ++r) {
        float4 q = P4[pb4 + gl + 16*r];       // {L, M, C, S}
        float p = EXP2F(fmaf(fj, q.x, -9.0f));   // m^j / 512
        cf2 F = p * mkc(q.z, q.w);
        cf2 Sv = (q.y + sg) * F;
        cf2 Vv = (q.y - sg) * F;
        if (gl == 0 && r == 0) { Sv.y = 0.0f; Vv.y = 0.0f; }  // DC imag dropped
        S[r] = Sv;
        ub[gl + 16*r] = Vv;
    }
    // bin 256 (group-uniform; computed by every lane, kept in registers)
    float4 q6 = P4[pb4 + 256];
    float pc6 = EXP2F(fmaf(fj, q6.x, -9.0f)) * q6.z;
    const float S6 = (q6.y + gf) * pc6;
    const float V6 = (q6.y - gf) * pc6;
    cfence();

    // ---- phase 2: Hann 3-tap, H into S regs
    float H6;
#pragma unroll
    for (int r = 0; r < 16; ++r) {
        const int c = gl + 16*r;
        const int im = (c == 0) ? 1 : c - 1;
        cf2 Vm = ub[im];
        if (c == 0) Vm.y = -Vm.y;             // hermitian V[-1] = conj V[1]
        cf2 Vp;
        if (r == 15) Vp = (gl == 15) ? mkc(V6, 0.0f) : ub[c + 1];
        else         Vp = ub[c + 1];
        S[r] = 0.5f * S[r] - 0.25f * (Vm + Vp);
    }
    H6 = 0.5f*S6 - 0.5f*ub[255].x;            // read before overwrite
    cfence();

    // write H over V (same-wave in-order)
#pragma unroll
    for (int r = 0; r < 16; ++r) ub[gl + 16*r] = S[r];
    cfence();

    // ---- phase 3: half-size packing -> Z (into S regs); scale already folded
    cf2 zw0 = mkc(hw_cos_rev((float)gl * (1.0f/512.0f)),
                  hw_sin_rev((float)gl * (1.0f/512.0f)));
    const float ZKC[16] = { 1.0f, 0.980785280403230f, 0.923879532511287f, 0.831469612302545f,
                            0.707106781186548f, 0.555570233019602f, 0.382683432365090f, 0.195090322016128f,
                            0.0f, -0.195090322016128f, -0.382683432365090f, -0.555570233019602f,
                            -0.707106781186548f, -0.831469612302545f, -0.923879532511287f, -0.980785280403230f };
    const float ZKS[16] = { 0.0f, 0.195090322016128f, 0.382683432365090f, 0.555570233019602f,
                            0.707106781186548f, 0.831469612302545f, 0.923879532511287f, 0.980785280403230f,
                            1.0f, 0.980785280403230f, 0.923879532511287f, 0.831469612302545f,
                            0.707106781186548f, 0.555570233019602f, 0.382683432365090f, 0.195090322016128f };
#pragma unroll
    for (int r = 0; r < 16; ++r) {
        const int c = gl + 16*r;
        cf2 Hk = S[r];
        cf2 cHm;
        if (r == 0) cHm = (gl == 0) ? mkc(H6, 0.0f) : cjg(ub[256 - c]);
        else        cHm = cjg(ub[256 - c]);
        cf2 w = cmulv(mkc(ZKC[r], ZKS[r]), zw0);
        cf2 A = Hk + cHm;
        cf2 B = Hk - cHm;
        S[r] = A + cmulv(ci(w), B);
    }
    cfence();   // all reads done before transpose writes (same buffer)

    // ---- FFT step 1: lane-local 16-pt IDFT over k2 (register axis); k1 = gl
    idft16_full(S);

    // ---- twiddle e^{2pi i k1 n1/256} via serial recurrence + transpose write (XOR-swizzled)
    {
        cf2 wt = cmulv(zw0, zw0);             // e^{2pi i gl/256} = zw0^2
        cf2 ww = mkc(1.0f, 0.0f);
#pragma unroll
        for (int n1 = 0; n1 < 16; ++n1) {
            ub[(gl << 4) | (n1 ^ gl)] = cmulv(S[n1], ww);
            ww = cmulv(ww, wt);
        }
    }
    cfence();

    // ---- transpose read: lane gl becomes n1 = gl; T[k1]
    cf2 T[16];
#pragma unroll
    for (int k1 = 0; k1 < 16; ++k1) T[k1] = ub[(k1 << 4) | (gl ^ k1)];

    // ---- FFT step 2: lane-local 16-pt IDFT over k1, outputs n2 = 0..7 only
    idft16_low8(T);

    // ---- store: z[n1 + 16 n2] -> out cf2 slot (j<<7) + gl + 16*n2
    cf2* o2 = (cf2*)out + (size_t)item * 16384 + (j << 7);
#pragma unroll
    for (int n2 = 0; n2 < 8; ++n2) o2[gl + 16*n2] = T[n2];
}

extern "C" void kernel_launch(void* const* d_in, const int* in_sizes, int n_in,
                              void* d_out, int out_size, void* d_ws, size_t ws_size,
                              hipStream_t stream)
{
    const float* sel   = (const float*)d_in[0];   // (8,32,4,4096) f32 -> [1024][4096]
    const float* items = (const float*)d_in[1];   // (4096,514) f32
    float* out = (float*)d_out;                   // [1024][32768] f32
    float* ws  = (float*)d_ws;

    // Scratch in d_out (all dead before kres rewrites out):
    float* WT     = out;                          // 4096*1024 floats
    float* rowmax = out + 4194304;                // 1024
    float* rowinv = out + 4195328;                // 1024
    int*   ncol   = (int*)(out + 4196352);        // 514
    int*   kidx   = (int*)(out + 4196866);        // 514*CAP
    float* kval   = (float*)(out + 4196866 + 514*CAP);
    float4* P4    = (float4*)ws;                  // 1024*257 float4

    kfused<<<1538, 256, 0, stream>>>(sel, items, rowmax, rowinv, kidx, kval, ncol);
    kT<<<dim3(64, 16), 256, 0, stream>>>(sel, rowmax, rowinv, WT);
    kspmm<<<dim3(4, 514), 256, 0, stream>>>(WT, kidx, kval, ncol, (float2*)ws);
    kres<<<8192, 256, 0, stream>>>(P4, out);
}

// Round 19
// 103.203 us; speedup vs baseline: 1.0271x; 1.0193x over previous
//
#include <hip/hip_runtime.h>

#define PI_F 3.14159265358979f
#define CAP 256

#if __has_builtin(__builtin_amdgcn_exp2f)
#define EXP2F(x) __builtin_amdgcn_exp2f(x)
#else
#define EXP2F(x) exp2f(x)
#endif

// hardware sin/cos: input in REVOLUTIONS (D = sin(S0*2pi)); used once for zw0 only.
__device__ __forceinline__ float hw_sin_rev(float q){ float r; asm("v_sin_f32 %0, %1" : "=v"(r) : "v"(q)); return r; }
__device__ __forceinline__ float hw_cos_rev(float q){ float r; asm("v_cos_f32 %0, %1" : "=v"(r) : "v"(q)); return r; }

// ---- packed complex type: <2 x float> so the backend can select v_pk_*_f32 ----
typedef float cf2 __attribute__((ext_vector_type(2)));
__device__ __forceinline__ cf2 mkc(float x, float y){ cf2 r; r.x = x; r.y = y; return r; }
__device__ __forceinline__ cf2 cmulv(cf2 a, cf2 b){
    cf2 bs = mkc(-b.y, b.x);
#if __has_builtin(__builtin_elementwise_fma)
    return __builtin_elementwise_fma(a.yy, bs, a.xx * b);
#else
    return a.xx * b + a.yy * bs;
#endif
}
__device__ __forceinline__ cf2 cjg(cf2 a){ return mkc(a.x, -a.y); }
__device__ __forceinline__ cf2 ci(cf2 a){ return mkc(-a.y, a.x); }   // i*a

// COMPILER-ONLY fence: LDS pipe is in-order per wave (buffers are wave-private),
// so cross-lane visibility needs no hardware drain — only a reorder barrier.
__device__ __forceinline__ void cfence() {
    asm volatile("" ::: "memory");
}

// ---- 16-pt unnormalized inverse DFT (sign +), in-place, fully unrolled ----
#define W16_C8 0.923879532511287f
#define W16_S8 0.382683432365090f
#define W16_R2 0.707106781186548f
__device__ __forceinline__ void idft16_full(cf2* x)
{
    cf2 u[16];
#pragma unroll
    for (int b0 = 0; b0 < 4; ++b0) {
        cf2 x0 = x[b0], x1 = x[4+b0], x2 = x[8+b0], x3 = x[12+b0];
        cf2 t0 = x0 + x2, t1 = x0 - x2;
        cf2 t2 = x1 + x3, t3 = x1 - x3;
        cf2 it3 = ci(t3);
        u[b0*4+0] = t0 + t2;
        u[b0*4+1] = t1 + it3;
        u[b0*4+2] = t0 - t2;
        u[b0*4+3] = t1 - it3;
    }
    u[4+1]  = cmulv(u[4+1],  mkc( W16_C8,  W16_S8));
    u[4+2]  = cmulv(u[4+2],  mkc( W16_R2,  W16_R2));
    u[4+3]  = cmulv(u[4+3],  mkc( W16_S8,  W16_C8));
    u[8+1]  = cmulv(u[8+1],  mkc( W16_R2,  W16_R2));
    u[8+2]  = ci(u[8+2]);
    u[8+3]  = cmulv(u[8+3],  mkc(-W16_R2,  W16_R2));
    u[12+1] = cmulv(u[12+1], mkc( W16_S8,  W16_C8));
    u[12+2] = cmulv(u[12+2], mkc(-W16_R2,  W16_R2));
    u[12+3] = cmulv(u[12+3], mkc(-W16_C8, -W16_S8));
#pragma unroll
    for (int a0 = 0; a0 < 4; ++a0) {
        cf2 x0 = u[a0], x1 = u[4+a0], x2 = u[8+a0], x3 = u[12+a0];
        cf2 t0 = x0 + x2, t1 = x0 - x2;
        cf2 t2 = x1 + x3, t3 = x1 - x3;
        cf2 it3 = ci(t3);
        x[a0+0]  = t0 + t2;
        x[a0+4]  = t1 + it3;
        x[a0+8]  = t0 - t2;
        x[a0+12] = t1 - it3;
    }
}
__device__ __forceinline__ void idft16_low8(cf2* x)
{
    cf2 u[16];
#pragma unroll
    for (int b0 = 0; b0 < 4; ++b0) {
        cf2 x0 = x[b0], x1 = x[4+b0], x2 = x[8+b0], x3 = x[12+b0];
        cf2 t0 = x0 + x2, t1 = x0 - x2;
        cf2 t2 = x1 + x3, t3 = x1 - x3;
        cf2 it3 = ci(t3);
        u[b0*4+0] = t0 + t2;
        u[b0*4+1] = t1 + it3;
        u[b0*4+2] = t0 - t2;
        u[b0*4+3] = t1 - it3;
    }
    u[4+1]  = cmulv(u[4+1],  mkc( W16_C8,  W16_S8));
    u[4+2]  = cmulv(u[4+2],  mkc( W16_R2,  W16_R2));
    u[4+3]  = cmulv(u[4+3],  mkc( W16_S8,  W16_C8));
    u[8+1]  = cmulv(u[8+1],  mkc( W16_R2,  W16_R2));
    u[8+2]  = ci(u[8+2]);
    u[8+3]  = cmulv(u[8+3],  mkc(-W16_R2,  W16_R2));
    u[12+1] = cmulv(u[12+1], mkc( W16_S8,  W16_C8));
    u[12+2] = cmulv(u[12+2], mkc(-W16_R2,  W16_R2));
    u[12+3] = cmulv(u[12+3], mkc(-W16_C8, -W16_S8));
#pragma unroll
    for (int a0 = 0; a0 < 4; ++a0) {
        cf2 x0 = u[a0], x1 = u[4+a0], x2 = u[8+a0], x3 = u[12+a0];
        cf2 t0 = x0 + x2, t1 = x0 - x2;
        cf2 t2 = x1 + x3, t3 = x1 - x3;
        cf2 it3 = ci(t3);
        x[a0+0] = t0 + t2;
        x[a0+4] = t1 + it3;
    }
}

// ---------------- kernel A: per-row softmax stats (max, 1/sumexp) ----------------
__global__ __launch_bounds__(256) void ksoft(const float* __restrict__ sel,
                                             float* __restrict__ rowmax,
                                             float* __restrict__ rowinv)
{
    const int row = blockIdx.x;
    const int tid = threadIdx.x;
    const float4* p4 = (const float4*)(sel + (size_t)row * 4096);
    float4 v[4];
    float mx = -3.0e38f;
#pragma unroll
    for (int i = 0; i < 4; ++i) {
        v[i] = p4[tid + (i<<8)];
        mx = fmaxf(mx, fmaxf(fmaxf(v[i].x, v[i].y), fmaxf(v[i].z, v[i].w)));
    }
#pragma unroll
    for (int o = 32; o >= 1; o >>= 1) mx = fmaxf(mx, __shfl_xor(mx, o));
    __shared__ float red[8];
    const int wv = tid >> 6;
    if ((tid & 63) == 0) red[wv] = mx;
    __syncthreads();
    mx = fmaxf(fmaxf(red[0], red[1]), fmaxf(red[2], red[3]));
    float s = 0.0f;
#pragma unroll
    for (int i = 0; i < 4; ++i) {
        s += __expf(v[i].x - mx) + __expf(v[i].y - mx) + __expf(v[i].z - mx) + __expf(v[i].w - mx);
    }
#pragma unroll
    for (int o = 32; o >= 1; o >>= 1) s += __shfl_xor(s, o);
    if ((tid & 63) == 0) red[4 + wv] = s;
    __syncthreads();
    if (tid == 0) {
        rowmax[row] = mx;
        rowinv[row] = 1.0f / (red[4] + red[5] + red[6] + red[7]);
    }
}

// ---------------- kernel A2: W^T[k][m] = softmax weight, tiled transpose ----------------
__global__ __launch_bounds__(256) void kT(const float* __restrict__ sel,
                                          const float* __restrict__ rowmax,
                                          const float* __restrict__ rowinv,
                                          float* __restrict__ WT)
{
    __shared__ float tile[64][65];
    __shared__ float smx[64], sinv[64];
    const int t = threadIdx.x;
    const int k0 = blockIdx.x * 64;
    const int m0 = blockIdx.y * 64;

    if (t < 64) { smx[t] = rowmax[m0 + t]; sinv[t] = rowinv[m0 + t]; }
    __syncthreads();

    const int m_l = t >> 4;
    const int k_l4 = (t & 15) << 2;
#pragma unroll
    for (int i = 0; i < 4; ++i) {
        const int ml = m_l + (i << 4);
        const float mxv = smx[ml], invv = sinv[ml];
        float4 v = *(const float4*)(sel + (size_t)(m0 + ml) * 4096 + k0 + k_l4);
        tile[k_l4 + 0][ml] = __expf(v.x - mxv) * invv;
        tile[k_l4 + 1][ml] = __expf(v.y - mxv) * invv;
        tile[k_l4 + 2][ml] = __expf(v.z - mxv) * invv;
        tile[k_l4 + 3][ml] = __expf(v.w - mxv) * invv;
    }
    __syncthreads();

    const int k_l = t >> 2;
    const int mb = (t & 3) << 2;
#pragma unroll
    for (int i = 0; i < 4; ++i) {
        const int ml = mb + (i << 4);
        float4 w = make_float4(tile[k_l][ml], tile[k_l][ml+1], tile[k_l][ml+2], tile[k_l][ml+3]);
        *(float4*)(WT + (size_t)(k0 + k_l) * 1024 + m0 + ml) = w;
    }
}

// ---------------- kernel B: build per-column nonzero lists of items (deterministic) -----
__global__ __launch_bounds__(256) void kfill(const float* __restrict__ items,
                                             int* __restrict__ kidx,
                                             float* __restrict__ kval,
                                             int* __restrict__ ncol)
{
    const int c = blockIdx.x;
    const int t = threadIdx.x;
    const int wv = t >> 6;
    const int lane = t & 63;
    __shared__ int wcnt[4];

    const int kc0 = wv << 10;
    float vv[16];
    int cnt = 0;
#pragma unroll
    for (int it = 0; it < 16; ++it) {
        const int k = kc0 + (it << 6) + lane;
        const float v = items[(size_t)k * 514 + c];
        vv[it] = v;
        unsigned long long mb = __ballot(v != 0.0f);
        cnt += __popcll(mb);
    }
    if (lane == 0) wcnt[wv] = cnt;
    __syncthreads();

    int base = 0;
#pragma unroll
    for (int q = 0; q < 4; ++q) if (q < wv) base += wcnt[q];

    const unsigned long long ltmask = (lane == 63) ? 0x7fffffffffffffffull
                                                   : ((1ull << lane) - 1ull);
#pragma unroll
    for (int it = 0; it < 16; ++it) {
        const float v = vv[it];
        const bool nz = (v != 0.0f);
        unsigned long long mb = __ballot(nz);
        if (nz) {
            const int slot = base + __popcll(mb & ltmask);
            if (slot < CAP) {
                kidx[c * CAP + slot] = kc0 + (it << 6) + lane;
                kval[c * CAP + slot] = v;
            }
        }
        base += __popcll(mb);
    }
    if (t == 0) ncol[c] = wcnt[0] + wcnt[1] + wcnt[2] + wcnt[3];
}

// ---------------- kernel B2: sparse matmul + transform -> P4 (float4 {L,M,C,S} per bin) ----
__global__ __launch_bounds__(256) void kspmm(const float* __restrict__ WT,
                                             const int* __restrict__ kidx,
                                             const float* __restrict__ kval,
                                             const int* __restrict__ ncol,
                                             float2* __restrict__ P2)
{
    __shared__ int   ski[CAP];
    __shared__ float skv[CAP];
    const int c = blockIdx.y;
    const int m = (blockIdx.x << 8) + threadIdx.x;
    const int nn = min(ncol[c], CAP);
    if (threadIdx.x < nn) {
        ski[threadIdx.x] = kidx[c * CAP + threadIdx.x];
        skv[threadIdx.x] = kval[c * CAP + threadIdx.x];
    }
    __syncthreads();

    float acc = 0.0f;
    int i = 0;
    for (; i + 4 <= nn; i += 4) {
        const int k0 = ski[i], k1 = ski[i+1], k2 = ski[i+2], k3 = ski[i+3];
        const float v0 = skv[i], v1 = skv[i+1], v2 = skv[i+2], v3 = skv[i+3];
        const float w0 = WT[(size_t)k0 * 1024 + m];
        const float w1 = WT[(size_t)k1 * 1024 + m];
        const float w2 = WT[(size_t)k2 * 1024 + m];
        const float w3 = WT[(size_t)k3 * 1024 + m];
        acc = fmaf(v0, w0, acc);
        acc = fmaf(v1, w1, acc);
        acc = fmaf(v2, w2, acc);
        acc = fmaf(v3, w3, acc);
    }
    for (; i < nn; ++i) {
        acc = fmaf(skv[i], WT[(size_t)ski[i] * 1024 + m], acc);
    }

    const float x = acc;
    if (c < 257) {
        float mm = 0.9999f / (1.0f + __expf(-x));
        P2[((size_t)m * 257 + c) * 2] = make_float2(__log2f(mm), mm);
    } else {
        float e2 = __expf(2.0f * x);
        float th = (e2 - 1.0f) / (e2 + 1.0f);
        float ph = PI_F * th;
        float sn, cs;
        __sincosf(ph, &sn, &cs);
        P2[((size_t)m * 257 + (c - 257)) * 2 + 1] = make_float2(cs, sn);
    }
}

// ---------------- kernel C: 16 lanes per j-block, radix-16^2 IFFT, packed-f32 complex ----
// 1/512 folded into exp2; serial cmulv twiddle recurrence; XOR-swizzled transpose.
__global__ __launch_bounds__(256) void kres(const float4* __restrict__ P4, float* __restrict__ out)
{
    const int tid = threadIdx.x;
    const int lane = tid & 63;
    const int wv = tid >> 6;
    const int g = lane >> 4;
    const int gl = lane & 15;
    const int item = blockIdx.x >> 3;
    const int jg = blockIdx.x & 7;

    __shared__ cf2 U[16 * 256];
    cf2* ub = U + (wv * 4 + g) * 256;

    const int j = jg * 16 + wv * 4 + g;
    const float fj = (float)j;
    const float gf = (j > 0) ? 1.0f : 0.0f;
    const float sg = (gl & 1) ? -gf : gf;     // (-1)^c * gf, c = gl+16r

    const int pb4 = item * 257;

    // ---- phase 1: load bins, build S (regs, pre-scaled by 1/512) and V -> LDS
    cf2 S[16];
#pragma unroll
    for (int r = 0; r < 16; ++r) {
        float4 q = P4[pb4 + gl + 16*r];       // {L, M, C, S}
        float p = EXP2F(fmaf(fj, q.x, -9.0f));   // m^j / 512
        cf2 F = p * mkc(q.z, q.w);
        cf2 Sv = (q.y + sg) * F;
        cf2 Vv = (q.y - sg) * F;
        if (gl == 0 && r == 0) { Sv.y = 0.0f; Vv.y = 0.0f; }  // DC imag dropped
        S[r] = Sv;
        ub[gl + 16*r] = Vv;
    }
    // bin 256 (group-uniform; computed by every lane, kept in registers)
    float4 q6 = P4[pb4 + 256];
    float pc6 = EXP2F(fmaf(fj, q6.x, -9.0f)) * q6.z;
    const float S6 = (q6.y + gf) * pc6;
    const float V6 = (q6.y - gf) * pc6;
    cfence();

    // ---- phase 2: Hann 3-tap, H into S regs
    float H6;
#pragma unroll
    for (int r = 0; r < 16; ++r) {
        const int c = gl + 16*r;
        const int im = (c == 0) ? 1 : c - 1;
        cf2 Vm = ub[im];
        if (c == 0) Vm.y = -Vm.y;             // hermitian V[-1] = conj V[1]
        cf2 Vp;
        if (r == 15) Vp = (gl == 15) ? mkc(V6, 0.0f) : ub[c + 1];
        else         Vp = ub[c + 1];
        S[r] = 0.5f * S[r] - 0.25f * (Vm + Vp);
    }
    H6 = 0.5f*S6 - 0.5f*ub[255].x;            // read before overwrite
    cfence();

    // write H over V (same-wave in-order)
#pragma unroll
    for (int r = 0; r < 16; ++r) ub[gl + 16*r] = S[r];
    cfence();

    // ---- phase 3: half-size packing -> Z (into S regs); scale already folded
    cf2 zw0 = mkc(hw_cos_rev((float)gl * (1.0f/512.0f)),
                  hw_sin_rev((float)gl * (1.0f/512.0f)));
    const float ZKC[16] = { 1.0f, 0.980785280403230f, 0.923879532511287f, 0.831469612302545f,
                            0.707106781186548f, 0.555570233019602f, 0.382683432365090f, 0.195090322016128f,
                            0.0f, -0.195090322016128f, -0.382683432365090f, -0.555570233019602f,
                            -0.707106781186548f, -0.831469612302545f, -0.923879532511287f, -0.980785280403230f };
    const float ZKS[16] = { 0.0f, 0.195090322016128f, 0.382683432365090f, 0.555570233019602f,
                            0.707106781186548f, 0.831469612302545f, 0.923879532511287f, 0.980785280403230f,
                            1.0f, 0.980785280403230f, 0.923879532511287f, 0.831469612302545f,
                            0.707106781186548f, 0.555570233019602f, 0.382683432365090f, 0.195090322016128f };
#pragma unroll
    for (int r = 0; r < 16; ++r) {
        const int c = gl + 16*r;
        cf2 Hk = S[r];
        cf2 cHm;
        if (r == 0) cHm = (gl == 0) ? mkc(H6, 0.0f) : cjg(ub[256 - c]);
        else        cHm = cjg(ub[256 - c]);
        cf2 w = cmulv(mkc(ZKC[r], ZKS[r]), zw0);
        cf2 A = Hk + cHm;
        cf2 B = Hk - cHm;
        S[r] = A + cmulv(ci(w), B);
    }
    cfence();   // all reads done before transpose writes (same buffer)

    // ---- FFT step 1: lane-local 16-pt IDFT over k2 (register axis); k1 = gl
    idft16_full(S);

    // ---- twiddle e^{2pi i k1 n1/256} via serial recurrence + transpose write (XOR-swizzled)
    {
        cf2 wt = cmulv(zw0, zw0);             // e^{2pi i gl/256} = zw0^2
        cf2 ww = mkc(1.0f, 0.0f);
#pragma unroll
        for (int n1 = 0; n1 < 16; ++n1) {
            ub[(gl << 4) | (n1 ^ gl)] = cmulv(S[n1], ww);
            ww = cmulv(ww, wt);
        }
    }
    cfence();

    // ---- transpose read: lane gl becomes n1 = gl; T[k1]
    cf2 T[16];
#pragma unroll
    for (int k1 = 0; k1 < 16; ++k1) T[k1] = ub[(k1 << 4) | (gl ^ k1)];

    // ---- FFT step 2: lane-local 16-pt IDFT over k1, outputs n2 = 0..7 only
    idft16_low8(T);

    // ---- store: z[n1 + 16 n2] -> out cf2 slot (j<<7) + gl + 16*n2
    cf2* o2 = (cf2*)out + (size_t)item * 16384 + (j << 7);
#pragma unroll
    for (int n2 = 0; n2 < 8; ++n2) o2[gl + 16*n2] = T[n2];
}

extern "C" void kernel_launch(void* const* d_in, const int* in_sizes, int n_in,
                              void* d_out, int out_size, void* d_ws, size_t ws_size,
                              hipStream_t stream)
{
    const float* sel   = (const float*)d_in[0];   // (8,32,4,4096) f32 -> [1024][4096]
    const float* items = (const float*)d_in[1];   // (4096,514) f32
    float* out = (float*)d_out;                   // [1024][32768] f32
    float* ws  = (float*)d_ws;

    // Scratch in d_out (all dead before kres rewrites out):
    float* WT     = out;                          // 4096*1024 floats
    float* rowmax = out + 4194304;                // 1024
    float* rowinv = out + 4195328;                // 1024
    int*   ncol   = (int*)(out + 4196352);        // 514
    int*   kidx   = (int*)(out + 4196866);        // 514*CAP
    float* kval   = (float*)(out + 4196866 + 514*CAP);
    float4* P4    = (float4*)ws;                  // 1024*257 float4

    ksoft<<<1024, 256, 0, stream>>>(sel, rowmax, rowinv);
    kT<<<dim3(64, 16), 256, 0, stream>>>(sel, rowmax, rowinv, WT);
    kfill<<<514, 256, 0, stream>>>(items, kidx, kval, ncol);
    kspmm<<<dim3(4, 514), 256, 0, stream>>>(WT, kidx, kval, ncol, (float2*)ws);
    kres<<<8192, 256, 0, stream>>>(P4, out);
}